// Round 9
// baseline (40.354 us; speedup 1.0000x reference)
//
#include <hip/hip_runtime.h>

// Exact decision boundary for  RN_f32(inter/uni) > (float)0.7 :
//   c = 0.7f = 0x3f333333, succ(c) = 0x3f333334 (even mantissa).
//   RN(x) > c  <=>  x >= M  where M = (c + succ(c))/2 (tie rounds to even
//   = succ(c) > c, so ">=" is correct).  M = 23488103 * 2^-25 (25 sig bits),
//   uni has <=24 sig bits  =>  M*(double)uni is EXACT, comparison is exact.
//   uni >= 2 always here (every box area >= 1), so uni==0 never occurs.
#define M_BOUND 0.7000000178813934326171875

__device__ __forceinline__ unsigned long long make_key(unsigned int sbits,
                                                       unsigned int idx) {
    // descending score, ascending index tie-break (stable argsort(-score))
    return (((unsigned long long)(~sbits)) << 32) | idx;
}

// ---------------------------------------------------------------------------
// Kernel 1: ORIGINAL-index-space pair kernel.  grid = (nb, nb) tile pairs,
// block = 256.  For tile (bi, bj): lane owns 4 j's (m*64+l), wave w owns
// i-quarter kbase=w*64.  Per pair: dir = key_i < key_j (= "i precedes j in
// the sorted order", exact incl. stable tie-break; i==j gives dir=false so
// self-pairs vanish).  rank_j = sum(dir) over all i; sup_j = OR(IoU-hit &&
// dir).  Cheap f32 filter + wave-level __any gates the exact f64 compare.
// Block epilogue: LDS-reduce the 4 wave partials per j, pack
// (supcount<<16)|rank into one u32, write part[bi*N + j].
// NO sort, NO scatter, NO diagonal special case.
// ---------------------------------------------------------------------------
__global__ __launch_bounds__(256)
void nms_pair(const float4* __restrict__ bbox,
              const float* __restrict__ score,
              unsigned int* __restrict__ part, int N)
{
    __shared__ __align__(16) char smem_raw[256 * 16 + 256 * 4 + 256 * 8];
    float4*             tile  = (float4*)smem_raw;
    float*              tarea = (float*)(smem_raw + 256 * 16);
    unsigned long long* tkey  = (unsigned long long*)(smem_raw + 256 * 20);

    const int bi  = blockIdx.x;
    const int bj  = blockIdx.y;
    const int tid = threadIdx.x;
    const int w   = tid >> 6;
    const int l   = tid & 63;

    {
        const int i = bi * 256 + tid;
        const float4 bb = bbox[i];
        tile[tid]  = bb;
        tarea[tid] = (bb.z - bb.x) * (bb.w - bb.y);   // single-rounded, as np
        tkey[tid]  = make_key(__float_as_uint(score[i]), (unsigned int)i);
    }
    __syncthreads();

    float4             jb[4];
    float              aj[4];
    unsigned long long jkey[4];
    #pragma unroll
    for (int m = 0; m < 4; ++m) {
        const int j = bj * 256 + m * 64 + l;
        jb[m]   = bbox[j];
        aj[m]   = (jb[m].z - jb[m].x) * (jb[m].w - jb[m].y);
        jkey[m] = make_key(__float_as_uint(score[j]), (unsigned int)j);
    }

    unsigned int c[4]   = {0u, 0u, 0u, 0u};
    unsigned int sup[4] = {0u, 0u, 0u, 0u};
    const int kbase = w * 64;

    #pragma unroll 2
    for (int k = 0; k < 64; ++k) {
        const float4             bo = tile[kbase + k];
        const float              ai = tarea[kbase + k];
        const unsigned long long ik = tkey[kbase + k];
        #pragma unroll
        for (int m = 0; m < 4; ++m) {
            const float iy1 = fmaxf(bo.x, jb[m].x);
            const float ix1 = fmaxf(bo.y, jb[m].y);
            const float iy2 = fminf(bo.z, jb[m].z);
            const float ix2 = fminf(bo.w, jb[m].w);
            const float ih  = fmaxf(iy2 - iy1, 0.0f);
            const float iw  = fmaxf(ix2 - ix1, 0.0f);
            float inter = ih * iw;
            const float s = ai + aj[m];
            const bool dir = (ik < jkey[m]);        // i precedes j (exact)
            c[m] += dir ? 1u : 0u;                  // rank accumulation
            // wave-level gate: cheap conservative filter, one scalar branch.
            // exact hit needs inter/s >= M/(1+M) ~= 0.41176; filter fires at
            // >= 0.69/1.69*(1 +- 2^-23) ~= 0.40828: margin 0.85% >> rounding.
            if (__any(fmaf(1.69f, inter, -0.69f * s) > 0.0f)) {
                asm volatile("" : "+v"(inter));     // block (s - ih*iw) -> fma
                const float uni = s - inter;
                const bool hit  = ((double)inter >= M_BOUND * (double)uni);
                sup[m] |= (hit && dir) ? 1u : 0u;
            }
        }
    }

    // epilogue: reduce 4 wave-partials per j.  pack (sup<<16) | count
    // (count <= 64 per wave, block sum <= 256: fits low16; supcount <= 4).
    __syncthreads();
    unsigned int* red = (unsigned int*)smem_raw;    // reuse tile LDS
    #pragma unroll
    for (int m = 0; m < 4; ++m)
        red[w * 256 + m * 64 + l] = (sup[m] ? 0x10000u : 0u) + c[m];
    __syncthreads();
    const unsigned int tot = red[tid] + red[256 + tid] +
                             red[512 + tid] + red[768 + tid];
    part[(size_t)bi * N + bj * 256 + tid] = tot;
}

// ---------------------------------------------------------------------------
// Kernel 2: finalize.  tot = sum of 32 block-partials per j:
// rank = tot & 0xFFFF (sum of per-block dir counts = exact sort position),
// suppressed = (tot >> 16) != 0.  Scatter masked box + keep flag to the
// sorted slot.  d_out layout: [N*4 floats boxes][N floats keep].
// ---------------------------------------------------------------------------
__global__ __launch_bounds__(256)
void nms_finalize(const float4* __restrict__ bbox,
                  const unsigned int* __restrict__ part,
                  float* __restrict__ out, int N)
{
    const int j = blockIdx.x * 256 + threadIdx.x;
    unsigned int tot = 0;
    #pragma unroll 8
    for (int bi = 0; bi < 32; ++bi)
        tot += part[(size_t)bi * N + j];
    const unsigned int r = tot & 0xFFFFu;
    const float s = (tot >> 16) ? 0.0f : 1.0f;
    const float4 b = bbox[j];
    float4 o;
    o.x = b.x * s; o.y = b.y * s; o.z = b.z * s; o.w = b.w * s;
    ((float4*)out)[r] = o;
    out[N * 4 + r] = s;
}

extern "C" void kernel_launch(void* const* d_in, const int* in_sizes, int n_in,
                              void* d_out, int out_size, void* d_ws, size_t ws_size,
                              hipStream_t stream) {
    const float* bbox  = (const float*)d_in[0];   // [1, N, 4] (y1,x1,y2,x2)
    const float* score = (const float*)d_in[1];   // [1, N]
    const int N = in_sizes[1];                    // 8192
    const int nb = N / 256;                       // 32

    unsigned int* part = (unsigned int*)d_ws;     // nb * N * 4 B = 1 MB

    nms_pair<<<dim3(nb, nb), 256, 0, stream>>>((const float4*)bbox, score,
                                               part, N);
    nms_finalize<<<nb, 256, 0, stream>>>((const float4*)bbox, part,
                                         (float*)d_out, N);
}